// Round 1
// baseline (1618.023 us; speedup 1.0000x reference)
//
#include <hip/hip_runtime.h>
#include <math.h>

#define Hd 128
#define Ln 64
#define Bsz 8

// T layout: T[((b*Ln + i)*Ln + j)*Hd + c], 8*64*64*128*4 = 16 MB in d_ws.
// Only valid cells (j < Ln - i) are ever written/read; row 0 is initialized
// from words_feats, so no zero-init of T is required.

__global__ void init_kernel(const float* __restrict__ wf, float* __restrict__ T) {
    int idx = blockIdx.x * 256 + threadIdx.x;   // 0..65535
    int b = idx >> 13;                           // 8192 elements per batch row-0 plane
    int rest = idx & 8191;                       // j*128 + c
    T[(size_t)b * (Ln * Ln * Hd) + rest] = wf[idx];
}

__global__ __launch_bounds__(256, 2)
void step_kernel(float* __restrict__ T,
                 const float* __restrict__ Wl, const float* __restrict__ blp,
                 const float* __restrict__ Wr, const float* __restrict__ brp,
                 const float* __restrict__ Wrep, const float* __restrict__ brepp,
                 const float* __restrict__ Wsv, const float* __restrict__ bsp,
                 int i)
{
    __shared__ float sWrep[Hd * Hd];   // 64 KB
    __shared__ float sLt[8 * Hd];      // 4 KB
    __shared__ float sRt[8 * Hd];      // 4 KB
    __shared__ float sHt[8 * Hd];      // 4 KB
    __shared__ float sWl[Hd], sWr[Hd], sWs[Hd], sBrep[Hd];  // 2 KB
    __shared__ float sWgt[8][2];
    __shared__ float sPart[4][4];      // per-wave partial logits
    __shared__ float sAcc[Hd];

    const int tid = threadIdx.x;
    const int nj = Ln - i;
    const int b = blockIdx.x / nj;
    const int j = blockIdx.x % nj;

    const float bl = blp[0], br = brp[0], bs = bsp[0];

    for (int idx = tid; idx < Hd * Hd; idx += 256) sWrep[idx] = Wrep[idx];
    if (tid < Hd) {
        sWl[tid] = Wl[tid]; sWr[tid] = Wr[tid];
        sWs[tid] = Wsv[tid]; sBrep[tid] = brepp[tid];
    }
    __syncthreads();

    const int c  = tid & 127;     // output column
    const int rg = tid >> 7;      // row-group 0/1 -> rows rg*4..rg*4+3
    const int g  = tid >> 5;      // dot-product group (one per row, 32 lanes)
    const int lg = tid & 31;
    const int wv = tid >> 6;      // wave id 0..3

    float m = -INFINITY, s = 0.f, accv = 0.f;

    const float* Tb = T + (size_t)b * (Ln * Ln * Hd);

    for (int kb = 0; kb < i; kb += 8) {
        int nvalid = i - kb; if (nvalid > 8) nvalid = 8;

        // ---- load left/right tiles (8 rows x 128), coalesced ----
        #pragma unroll
        for (int q = 0; q < 4; ++q) {
            int idx = tid + q * 256;
            int r = idx >> 7, cc = idx & 127;
            int k = kb + r;
            int kc = (k < i) ? k : (i - 1);   // clamp invalid rows to safe indices
            sLt[idx] = Tb[((size_t)kc * Ln + j) * Hd + cc];
            sRt[idx] = Tb[((size_t)(i - 1 - kc) * Ln + (j + kc + 1)) * Hd + cc];
        }
        __syncthreads();

        // ---- per-row dot products sl, sr (32-lane groups, float4) ----
        float4 lv  = *(const float4*)&sLt[g * Hd + lg * 4];
        float4 rv  = *(const float4*)&sRt[g * Hd + lg * 4];
        float4 wlv = *(const float4*)&sWl[lg * 4];
        float4 wrv = *(const float4*)&sWr[lg * 4];
        float dl = lv.x * wlv.x + lv.y * wlv.y + lv.z * wlv.z + lv.w * wlv.w;
        float dr = rv.x * wrv.x + rv.y * wrv.y + rv.z * wrv.z + rv.w * wrv.w;
        #pragma unroll
        for (int off = 16; off > 0; off >>= 1) {
            dl += __shfl_xor(dl, off);
            dr += __shfl_xor(dr, off);
        }
        if (lg == 0) {
            float sl = dl + bl, sr = dr + br;
            float mm = fmaxf(sl, sr);
            float e0 = __expf(sl - mm), e1 = __expf(sr - mm);
            float inv = 1.f / (e0 + e1);
            sWgt[g][0] = e0 * inv; sWgt[g][1] = e1 * inv;
        }
        __syncthreads();

        // ---- h_hat = w0*left + w1*right ----
        #pragma unroll
        for (int q = 0; q < 4; ++q) {
            int idx = tid + q * 256;
            int r = idx >> 7;
            sHt[idx] = sWgt[r][0] * sLt[idx] + sWgt[r][1] * sRt[idx];
        }
        __syncthreads();

        // ---- matvec: temp = relu(h_hat @ Wrep + brep) + h_hat, 4 rows/thread ----
        float a0 = 0.f, a1 = 0.f, a2 = 0.f, a3 = 0.f;
        const float* h0p = &sHt[(rg * 4 + 0) * Hd];
        const float* h1p = &sHt[(rg * 4 + 1) * Hd];
        const float* h2p = &sHt[(rg * 4 + 2) * Hd];
        const float* h3p = &sHt[(rg * 4 + 3) * Hd];
        #pragma unroll 4
        for (int h = 0; h < Hd; h += 4) {
            float w0 = sWrep[(h + 0) * Hd + c];
            float w1 = sWrep[(h + 1) * Hd + c];
            float w2 = sWrep[(h + 2) * Hd + c];
            float w3 = sWrep[(h + 3) * Hd + c];
            float4 v0 = *(const float4*)&h0p[h];
            float4 v1 = *(const float4*)&h1p[h];
            float4 v2 = *(const float4*)&h2p[h];
            float4 v3 = *(const float4*)&h3p[h];
            a0 += v0.x * w0 + v0.y * w1 + v0.z * w2 + v0.w * w3;
            a1 += v1.x * w0 + v1.y * w1 + v1.z * w2 + v1.w * w3;
            a2 += v2.x * w0 + v2.y * w1 + v2.z * w2 + v2.w * w3;
            a3 += v3.x * w0 + v3.y * w1 + v3.z * w2 + v3.w * w3;
        }
        float bcv = sBrep[c];
        float t0 = fmaxf(a0 + bcv, 0.f) + h0p[c];
        float t1 = fmaxf(a1 + bcv, 0.f) + h1p[c];
        float t2 = fmaxf(a2 + bcv, 0.f) + h2p[c];
        float t3 = fmaxf(a3 + bcv, 0.f) + h3p[c];

        // ---- logits: reduce temp*Ws over c (64-lane shuffle + cross-wave LDS) ----
        float wsc = sWs[c];
        float p0 = t0 * wsc, p1 = t1 * wsc, p2 = t2 * wsc, p3 = t3 * wsc;
        #pragma unroll
        for (int off = 32; off > 0; off >>= 1) {
            p0 += __shfl_xor(p0, off);
            p1 += __shfl_xor(p1, off);
            p2 += __shfl_xor(p2, off);
            p3 += __shfl_xor(p3, off);
        }
        if ((tid & 63) == 0) {
            sPart[wv][0] = p0; sPart[wv][1] = p1;
            sPart[wv][2] = p2; sPart[wv][3] = p3;
        }
        __syncthreads();

        // ---- online softmax update over k ----
        float lr[8];
        #pragma unroll
        for (int r = 0; r < 8; ++r) {
            int gg = r >> 2, q = r & 3;
            float lval = sPart[gg * 2][q] + sPart[gg * 2 + 1][q] + bs;
            lr[r] = (r < nvalid) ? lval : -INFINITY;
        }
        float nm = m;
        #pragma unroll
        for (int r = 0; r < 8; ++r) nm = fmaxf(nm, lr[r]);
        float f = __expf(m - nm);
        float er[8];
        float se = 0.f;
        #pragma unroll
        for (int r = 0; r < 8; ++r) { er[r] = __expf(lr[r] - nm); se += er[r]; }
        s = s * f + se;
        accv = accv * f
             + er[rg * 4 + 0] * t0 + er[rg * 4 + 1] * t1
             + er[rg * 4 + 2] * t2 + er[rg * 4 + 3] * t3;
        m = nm;
        __syncthreads();
    }

    // ---- finalize: invalid-k entries add (64-i)*exp(bs) to denominator ----
    float mf = fmaxf(m, bs);
    float fm = __expf(m - mf);
    float sf = s * fm + (float)(Ln - i) * __expf(bs - mf);
    accv *= fm;
    if (rg == 1) sAcc[c] = accv;
    __syncthreads();
    if (rg == 0) {
        float res = (accv + sAcc[c]) / sf;
        T[(((size_t)b * Ln + i) * Ln + j) * Hd + c] = res;
    }
}

__global__ void out_kernel(const float* __restrict__ T, float* __restrict__ out) {
    int t = blockIdx.x * 256 + threadIdx.x;   // 1024 total
    int b = t >> 7, cc = t & 127;
    out[t] = T[(((size_t)b * Ln + (Ln - 1)) * Ln + 0) * Hd + cc];
}

extern "C" void kernel_launch(void* const* d_in, const int* in_sizes, int n_in,
                              void* d_out, int out_size, void* d_ws, size_t ws_size,
                              hipStream_t stream)
{
    const float* wf   = (const float*)d_in[0];
    // d_in[1] = words_masks: unused by the reference math (all ones)
    const float* Wl   = (const float*)d_in[2];
    const float* bl   = (const float*)d_in[3];
    const float* Wr   = (const float*)d_in[4];
    const float* br   = (const float*)d_in[5];
    const float* Wrep = (const float*)d_in[6];
    const float* brep = (const float*)d_in[7];
    const float* Ws   = (const float*)d_in[8];
    const float* bs   = (const float*)d_in[9];

    float* T   = (float*)d_ws;    // needs 16 MB
    float* out = (float*)d_out;

    init_kernel<<<256, 256, 0, stream>>>(wf, T);
    for (int i = 1; i < Ln; ++i) {
        step_kernel<<<Bsz * (Ln - i), 256, 0, stream>>>(T, Wl, bl, Wr, br,
                                                        Wrep, brep, Ws, bs, i);
    }
    out_kernel<<<4, 256, 0, stream>>>(T, out);
}

// Round 2
// 1178.577 us; speedup vs baseline: 1.3729x; 1.3729x over previous
//
#include <hip/hip_runtime.h>
#include <math.h>

#define Hd 128
#define Ln 64
#define Bsz 8
#define NW 8   // waves per block (512 threads)

// T layout: T[((b*Ln + i)*Ln + j)*Hd + c], 16 MB in d_ws.

__global__ void init_kernel(const float* __restrict__ wf, float* __restrict__ T) {
    int idx = blockIdx.x * 256 + threadIdx.x;   // 0..65535
    int b = idx >> 13;
    int rest = idx & 8191;
    T[(size_t)b * (Ln * Ln * Hd) + rest] = wf[idx];
}

// One block per (b,j) cell. 8 waves; wave wv handles k = wv, wv+8, ..., wv+8*(KB-1).
// KB chosen so 8*KB >= i. No k-loop: single batch covers all k.
template<int KB>
__global__ __launch_bounds__(512, 2)
void step_kernel(float* __restrict__ T,
                 const float* __restrict__ Wl, const float* __restrict__ blp,
                 const float* __restrict__ Wr, const float* __restrict__ brp,
                 const float* __restrict__ Wrep, const float* __restrict__ brepp,
                 const float* __restrict__ Wsv, const float* __restrict__ bsp,
                 int i)
{
    __shared__ __align__(16) float sW[Hd * Hd];      // 64 KB, transposed + XOR-swizzled
    __shared__ __align__(16) float sH[NW][KB][Hd];   // h_hat rows, wave-private
    __shared__ float sAccM[NW][Hd];                  // per-wave weighted sums
    __shared__ float sMS[NW][2];                     // per-wave (max, sumexp)

    const int tid = threadIdx.x;
    const int wv  = tid >> 6;
    const int ln  = tid & 63;
    const int nj  = Ln - i;
    const int b   = blockIdx.x / nj;
    const int j   = blockIdx.x - b * nj;

    const float bl = blp[0], br = brp[0], bs = bsp[0];
    const float2 wlv = *(const float2*)&Wl[2 * ln];
    const float2 wrv = *(const float2*)&Wr[2 * ln];

    const float* Tb = T + (size_t)b * (Ln * Ln * Hd);

    // ---- issue L/R row loads first (latency overlaps Wrep staging) ----
    float2 Lr[KB], Rr[KB];
    #pragma unroll
    for (int r = 0; r < KB; ++r) {
        int k = wv + NW * r;
        int kcl = k < i ? k : (i - 1);    // clamp invalid to a safe duplicate row
        Lr[r] = *(const float2*)(Tb + ((size_t)kcl * Ln + j) * Hd + 2 * ln);
        Rr[r] = *(const float2*)(Tb + ((size_t)(i - 1 - kcl) * Ln + (j + kcl + 1)) * Hd + 2 * ln);
    }

    // ---- stage Wrep transposed + swizzled: elem (h,c) -> sW[c*128 + ((h>>2 ^ (c&31))<<2 | (h&3))] ----
    #pragma unroll
    for (int it = 0; it < 8; ++it) {
        int idx4 = tid + it * 512;          // float4 index, 0..4095
        int h  = idx4 >> 5;                 // 0..127
        int c4 = (idx4 & 31) << 2;
        float4 v = *(const float4*)&Wrep[h * Hd + c4];
        float vv[4] = {v.x, v.y, v.z, v.w};
        #pragma unroll
        for (int q = 0; q < 4; ++q) {
            int c = c4 + q;
            sW[c * Hd + ((((h >> 2) ^ (c & 31)) << 2) | (h & 3))] = vv[q];
        }
    }

    // ---- per-wave: dot products sl, sr (butterfly over 64 lanes) ----
    float pl[KB], pr[KB];
    #pragma unroll
    for (int r = 0; r < KB; ++r) {
        pl[r] = Lr[r].x * wlv.x + Lr[r].y * wlv.y;
        pr[r] = Rr[r].x * wrv.x + Rr[r].y * wrv.y;
    }
    #pragma unroll
    for (int off = 32; off > 0; off >>= 1) {
        #pragma unroll
        for (int r = 0; r < KB; ++r) {
            pl[r] += __shfl_xor(pl[r], off);
            pr[r] += __shfl_xor(pr[r], off);
        }
    }

    // ---- 2-way softmax -> h_hat, write to wave-private LDS ----
    #pragma unroll
    for (int r = 0; r < KB; ++r) {
        float sl = pl[r] + bl, sr = pr[r] + br;
        float mm = fmaxf(sl, sr);
        float e0 = __expf(sl - mm), e1 = __expf(sr - mm);
        float inv = 1.f / (e0 + e1);
        float w0 = e0 * inv, w1 = e1 * inv;
        float2 hh;
        hh.x = w0 * Lr[r].x + w1 * Rr[r].x;
        hh.y = w0 * Lr[r].y + w1 * Rr[r].y;
        *(float2*)&sH[wv][r][2 * ln] = hh;
    }

    __syncthreads();   // sW visible to all waves

    // ---- matvec: lane owns cols c0=ln, c1=ln+64; w reused across KB rows ----
    const int c0 = ln, c1 = ln + 64;
    const int x0 = ln & 31;
    float acc0[KB], acc1[KB];
    #pragma unroll
    for (int r = 0; r < KB; ++r) { acc0[r] = 0.f; acc1[r] = 0.f; }
    const float* sW0 = &sW[c0 * Hd];
    const float* sW1 = &sW[c1 * Hd];
    #pragma unroll
    for (int hb = 0; hb < 32; ++hb) {
        const float4 w0v = *(const float4*)&sW0[(hb ^ x0) << 2];
        const float4 w1v = *(const float4*)&sW1[(hb ^ x0) << 2];
        #pragma unroll
        for (int r = 0; r < KB; ++r) {
            float4 hv = *(const float4*)&sH[wv][r][hb << 2];   // broadcast
            acc0[r] += hv.x * w0v.x + hv.y * w0v.y + hv.z * w0v.z + hv.w * w0v.w;
            acc1[r] += hv.x * w1v.x + hv.y * w1v.y + hv.z * w1v.z + hv.w * w1v.w;
        }
    }

    // ---- temp = relu(.+brep)+h_hat; logits ----
    float ws0 = Wsv[c0], ws1 = Wsv[c1];
    float bb0 = brepp[c0], bb1 = brepp[c1];
    float t0[KB], t1[KB], lg[KB];
    #pragma unroll
    for (int r = 0; r < KB; ++r) {
        float h0 = sH[wv][r][c0], h1 = sH[wv][r][c1];
        t0[r] = fmaxf(acc0[r] + bb0, 0.f) + h0;
        t1[r] = fmaxf(acc1[r] + bb1, 0.f) + h1;
        lg[r] = t0[r] * ws0 + t1[r] * ws1;
    }
    #pragma unroll
    for (int off = 32; off > 0; off >>= 1) {
        #pragma unroll
        for (int r = 0; r < KB; ++r) lg[r] += __shfl_xor(lg[r], off);
    }
    #pragma unroll
    for (int r = 0; r < KB; ++r)
        lg[r] = (wv + NW * r < i) ? (lg[r] + bs) : -INFINITY;

    // ---- per-wave softmax partials over its k rows ----
    float mw = -INFINITY;
    #pragma unroll
    for (int r = 0; r < KB; ++r) mw = fmaxf(mw, lg[r]);
    float mwc = fmaxf(mw, -1e30f);   // avoid (-inf)-(-inf)=NaN for waves with no valid k
    float sw_ = 0.f, a0 = 0.f, a1 = 0.f;
    #pragma unroll
    for (int r = 0; r < KB; ++r) {
        float e = __expf(lg[r] - mwc);
        sw_ += e; a0 += e * t0[r]; a1 += e * t1[r];
    }

    if (ln == 0) { sMS[wv][0] = mw; sMS[wv][1] = sw_; }
    sAccM[wv][c0] = a0;
    sAccM[wv][c1] = a1;
    __syncthreads();

    // ---- merge 8 waves; invalid k entries contribute (64-i)*exp(bs) to denom ----
    if (tid < Hd) {
        float M = bs;
        #pragma unroll
        for (int w = 0; w < NW; ++w) M = fmaxf(M, sMS[w][0]);
        float den = (float)(Ln - i) * __expf(bs - M);
        float num = 0.f;
        #pragma unroll
        for (int w = 0; w < NW; ++w) {
            float e = __expf(sMS[w][0] - M);
            den += e * sMS[w][1];
            num += e * sAccM[w][tid];
        }
        T[(((size_t)b * Ln + i) * Ln + j) * Hd + tid] = num / den;
    }
}

__global__ void out_kernel(const float* __restrict__ T, float* __restrict__ out) {
    int t = blockIdx.x * 256 + threadIdx.x;   // 1024 total
    int b = t >> 7, cc = t & 127;
    out[t] = T[(((size_t)b * Ln + (Ln - 1)) * Ln + 0) * Hd + cc];
}

extern "C" void kernel_launch(void* const* d_in, const int* in_sizes, int n_in,
                              void* d_out, int out_size, void* d_ws, size_t ws_size,
                              hipStream_t stream)
{
    const float* wf   = (const float*)d_in[0];
    const float* Wl   = (const float*)d_in[2];
    const float* bl   = (const float*)d_in[3];
    const float* Wr   = (const float*)d_in[4];
    const float* br   = (const float*)d_in[5];
    const float* Wrep = (const float*)d_in[6];
    const float* brep = (const float*)d_in[7];
    const float* Ws   = (const float*)d_in[8];
    const float* bs   = (const float*)d_in[9];

    float* T   = (float*)d_ws;    // 16 MB
    float* out = (float*)d_out;

    init_kernel<<<256, 256, 0, stream>>>(wf, T);
    for (int i = 1; i < Ln; ++i) {
        int grid = Bsz * (Ln - i);
        if (i <= 16)
            step_kernel<2><<<grid, 512, 0, stream>>>(T, Wl, bl, Wr, br, Wrep, brep, Ws, bs, i);
        else if (i <= 32)
            step_kernel<4><<<grid, 512, 0, stream>>>(T, Wl, bl, Wr, br, Wrep, brep, Ws, bs, i);
        else
            step_kernel<8><<<grid, 512, 0, stream>>>(T, Wl, bl, Wr, br, Wrep, brep, Ws, bs, i);
    }
    out_kernel<<<4, 256, 0, stream>>>(T, out);
}